// Round 10
// baseline (110.430 us; speedup 1.0000x reference)
//
#include <hip/hip_runtime.h>

// MixConv: depthwise conv, 3 groups of 64 channels, k=3/5/7, same padding.
// x: [32,192,112,112] f32; w_k: [64,1,k,k] f32; out: [32,192,112,112] f32.
//
// Round 10 = Round 9 with deeper register blocking: 4 rows x 4 cols per
// thread (tap rows K+3 per 4 output rows vs K+1 per 2 -> DS reads/quad
// -33%, window VALU -33%), TILE_H 28 -> 56 (halo refetch 1.14x -> 1.07x).
// Store discipline unchanged (R7 fix): per-thread dwordx4 nt stores whose
// wave-level lane runs are ascending contiguous full rows -> no write
// amplification. LSTRIDE 496 B (31 quads) keeps row-to-row bank rotation.

#define HW 112
#define TILE_H 56
#define QROW 28              // data quads per row
#define LSTRIDE 496          // 31 quads: pad + 28 data + pad + spare
#define NR_MAX (TILE_H + 6)  // 62 staged rows max (k=7)
#define C_TOTAL 192
#define N_BATCH 32

typedef float f4 __attribute__((ext_vector_type(4)));

template <int K>
__device__ __forceinline__ void conv_tile(const float* __restrict__ x,
                                          const float* __restrict__ w,
                                          float* __restrict__ out, char* lds,
                                          int cglob, int wc, int n, int tile0) {
  constexpr int PAD = (K - 1) / 2;
  constexpr int NR = TILE_H + K - 1;      // staged input rows
  constexpr int TOT = NR * QROW;          // staged 16B units
  constexpr int SITERS = (TOT + 255) / 256;
  constexpr int CTOT = (TILE_H / 4) * QROW;  // 392 4-row units per tile

  const int tid = threadIdx.x;
  const size_t plane = ((size_t)n * C_TOTAL + cglob) * (HW * HW);
  const float* xp = x + plane;

  // Block-uniform weights -> scalar loads / SGPR broadcast.
  float wr[K * K];
#pragma unroll
  for (int i = 0; i < K * K; ++i) wr[i] = w[wc * K * K + i];

  // ---- Stage rows [tile0-PAD, tile0+TILE_H+PAD) into LDS (zeros for
  // out-of-image rows); loads are full-wave ascending contiguous dwordx4.
  const f4 z4 = {0.f, 0.f, 0.f, 0.f};
  f4 sv[SITERS];
#pragma unroll
  for (int it = 0; it < SITERS; ++it) {
    const int unit = tid + it * 256;
    const int row = unit / QROW;
    const int cu = unit - row * QROW;
    const int ih = tile0 - PAD + row;
    const bool ok = (unit < TOT) && (ih >= 0) && (ih < HW);
    const int ihc = (ih < 0) ? 0 : ((ih > HW - 1) ? HW - 1 : ih);
    const f4 t = *(const f4*)(xp + (size_t)ihc * HW + cu * 4);
    sv[it] = ok ? t : z4;
  }
#pragma unroll
  for (int it = 0; it < SITERS; ++it) {
    const int unit = tid + it * 256;
    const int row = unit / QROW;
    const int cu = unit - row * QROW;
    if (unit < TOT) *(f4*)(lds + row * LSTRIDE + 16 + cu * 16) = sv[it];
  }
  // Zero the left/right pad quads (cols -4..0 and 112..116).
  if (tid < NR) *(f4*)(lds + tid * LSTRIDE) = z4;
  if (tid >= 128 && tid < 128 + NR)
    *(f4*)(lds + (tid - 128) * LSTRIDE + 29 * 16) = z4;
  __syncthreads();

  // ---- Compute: unit = 4-row-block*28 + q; each thread -> 4 rows x 4 cols.
  char* const outb = (char*)(out + plane + (size_t)tile0 * HW);
#pragma unroll
  for (int b = 0; b < 2; ++b) {
    const int unit = tid + b * 256;
    if (unit < CTOT) {
      const int rb4 = unit / QROW;
      const int q = unit - rb4 * QROW;
      const char* base = lds + rb4 * 4 * LSTRIDE + q * 16;

      float acc[4][4] = {{0.f, 0.f, 0.f, 0.f},
                         {0.f, 0.f, 0.f, 0.f},
                         {0.f, 0.f, 0.f, 0.f},
                         {0.f, 0.f, 0.f, 0.f}};
#pragma unroll
      for (int r = 0; r < K + 3; ++r) {  // tap rows feed outputs rb4*4+0..3
        const char* rbp = base + r * LSTRIDE;
        const f4 L = *(const f4*)(rbp);
        const f4 M = *(const f4*)(rbp + 16);
        const f4 R = *(const f4*)(rbp + 32);
        // Fully static-indexed -> registers.
        const float buf[12] = {L.x, L.y, L.z, L.w, M.x, M.y,
                               M.z, M.w, R.x, R.y, R.z, R.w};
#pragma unroll
        for (int o = 0; o < 4; ++o) {
          const int dy = r - o;  // compile-time tap row for output row o
          if (dy >= 0 && dy < K) {
#pragma unroll
            for (int dx = 0; dx < K; ++dx) {
              const float wt = wr[dy * K + dx];
#pragma unroll
              for (int j = 0; j < 4; ++j)
                acc[o][j] = fmaf(wt, buf[4 + j + dx - PAD], acc[o][j]);
            }
          }
        }
      }
      // 4 nt stores; each wave instruction's lane runs are ascending
      // contiguous full 448B rows -> full 64B lines, no amplification.
      char* const o0 = outb + (size_t)(rb4 * 4) * (HW * 4) + q * 16;
#pragma unroll
      for (int o = 0; o < 4; ++o) {
        f4 v = {acc[o][0], acc[o][1], acc[o][2], acc[o][3]};
        __builtin_nontemporal_store(v, (f4*)(o0 + (size_t)o * (HW * 4)));
      }
    }
  }
}

__global__ __launch_bounds__(256) void mixconv_lds(
    const float* __restrict__ x, const float* __restrict__ w3,
    const float* __restrict__ w5, const float* __restrict__ w7,
    float* __restrict__ out) {
  __shared__ __align__(16) char lds[NR_MAX * LSTRIDE];  // 30752 B
  const int cy = blockIdx.y;
  const int n = blockIdx.z;
  const int tile0 = blockIdx.x * TILE_H;
  if (cy < 64)
    conv_tile<3>(x, w3, out, lds, cy, cy, n, tile0);
  else if (cy < 128)
    conv_tile<5>(x, w5, out, lds, cy, cy - 64, n, tile0);
  else
    conv_tile<7>(x, w7, out, lds, cy, cy - 128, n, tile0);
}

extern "C" void kernel_launch(void* const* d_in, const int* in_sizes, int n_in,
                              void* d_out, int out_size, void* d_ws,
                              size_t ws_size, hipStream_t stream) {
  const float* x = (const float*)d_in[0];
  const float* w3 = (const float*)d_in[1];
  const float* w5 = (const float*)d_in[2];
  const float* w7 = (const float*)d_in[3];
  float* out = (float*)d_out;

  const dim3 grid(HW / TILE_H, C_TOTAL, N_BATCH);  // 2 x 192 x 32
  const dim3 block(256);
  mixconv_lds<<<grid, block, 0, stream>>>(x, w3, w5, w7, out);
}

// Round 11
// 109.362 us; speedup vs baseline: 1.0098x; 1.0098x over previous
//
#include <hip/hip_runtime.h>

// MixConv: depthwise conv, 3 groups of 64 channels, k=3/5/7, same padding.
// x: [32,192,112,112] f32; w_k: [64,1,k,k] f32; out: [32,192,112,112] f32.
//
// FINAL (= Round 9, best measured: 108.9 us). Structure:
//  - One fused dispatch; block = 256 thr; tile = 28 output rows x 112 cols.
//  - Stage (28+K-1) input rows into LDS (zero pad quads at both row ends,
//    LSTRIDE 496 B for bank rotation), barrier, compute from LDS.
//  - 2-row x 4-col register blocking: each thread's 12-float window per tap
//    row feeds TWO output rows (DS bytes/elt 6(K+1), -40% vs 1-row).
//  - Output stores are ext_vector dwordx4 + __builtin_nontemporal_store;
//    every wave store instruction covers ascending contiguous full 448 B
//    row-runs (full 64 B lines). This was the decisive fix: HIP struct-
//    float4 stores scalarize into 4x dword stores, and partial-line L2
//    eviction under load amplified WRITE_SIZE up to 3.7x (350 -> 118 us
//    when fixed).
// Counters at this config: WRITE 301 MB (exact), FETCH ~185 MB (L3-assisted,
// compulsory 308), dur ~109 us vs ~102 us compulsory floor + launch.

#define HW 112
#define TILE_H 28
#define QROW 28              // data quads per row
#define LSTRIDE 496          // 31 quads: 28 data + 2 zero pads + 1 spare
#define NR_MAX (TILE_H + 6)  // 34 staged rows max (k=7)
#define C_TOTAL 192
#define N_BATCH 32

typedef float f4 __attribute__((ext_vector_type(4)));

template <int K>
__device__ __forceinline__ void conv_tile(const float* __restrict__ x,
                                          const float* __restrict__ w,
                                          float* __restrict__ out, char* lds,
                                          int cglob, int wc, int n, int tile0) {
  constexpr int PAD = (K - 1) / 2;
  constexpr int NR = TILE_H + K - 1;      // staged input rows
  constexpr int TOT = NR * QROW;          // staged 16B units
  constexpr int SITERS = (TOT + 255) / 256;
  constexpr int CTOT = (TILE_H / 2) * QROW;  // 392 2-row units per tile

  const int tid = threadIdx.x;
  const size_t plane = ((size_t)n * C_TOTAL + cglob) * (HW * HW);
  const float* xp = x + plane;

  // Block-uniform weights -> scalar loads / SGPR broadcast.
  float wr[K * K];
#pragma unroll
  for (int i = 0; i < K * K; ++i) wr[i] = w[wc * K * K + i];

  // ---- Stage rows [tile0-PAD, tile0+TILE_H+PAD) into LDS (zeros for
  // out-of-image rows); loads are full-wave ascending contiguous dwordx4.
  const f4 z4 = {0.f, 0.f, 0.f, 0.f};
  f4 sv[SITERS];
#pragma unroll
  for (int it = 0; it < SITERS; ++it) {
    const int unit = tid + it * 256;
    const int row = unit / QROW;
    const int cu = unit - row * QROW;
    const int ih = tile0 - PAD + row;
    const bool ok = (unit < TOT) && (ih >= 0) && (ih < HW);
    const int ihc = (ih < 0) ? 0 : ((ih > HW - 1) ? HW - 1 : ih);
    const f4 t = *(const f4*)(xp + (size_t)ihc * HW + cu * 4);
    sv[it] = ok ? t : z4;
  }
#pragma unroll
  for (int it = 0; it < SITERS; ++it) {
    const int unit = tid + it * 256;
    const int row = unit / QROW;
    const int cu = unit - row * QROW;
    if (unit < TOT) *(f4*)(lds + row * LSTRIDE + 16 + cu * 16) = sv[it];
  }
  // Zero the left/right pad quads (cols -4..0 and 112..116).
  if (tid < NR) *(f4*)(lds + tid * LSTRIDE) = z4;
  if (tid >= 128 && tid < 128 + NR)
    *(f4*)(lds + (tid - 128) * LSTRIDE + 29 * 16) = z4;
  __syncthreads();

  // ---- Compute: unit = row-pair*28 + q; each thread -> 2 rows x 4 cols.
  char* const outb = (char*)(out + plane + (size_t)tile0 * HW);
#pragma unroll
  for (int b = 0; b < 2; ++b) {
    const int unit = tid + b * 256;
    if (unit < CTOT) {
      const int rp = unit / QROW;
      const int q = unit - rp * QROW;
      const char* base = lds + rp * 2 * LSTRIDE + q * 16;

      float acc[2][4] = {{0.f, 0.f, 0.f, 0.f}, {0.f, 0.f, 0.f, 0.f}};
#pragma unroll
      for (int r = 0; r < K + 1; ++r) {  // tap rows for output rows rp*2(+1)
        const char* rb = base + r * LSTRIDE;
        const f4 L = *(const f4*)(rb);
        const f4 M = *(const f4*)(rb + 16);
        const f4 R = *(const f4*)(rb + 32);
        // Fully static-indexed -> registers.
        const float buf[12] = {L.x, L.y, L.z, L.w, M.x, M.y,
                               M.z, M.w, R.x, R.y, R.z, R.w};
#pragma unroll
        for (int o = 0; o < 2; ++o) {
          const int dy = r - o;  // compile-time tap row for output row o
          if (dy >= 0 && dy < K) {
#pragma unroll
            for (int dx = 0; dx < K; ++dx) {
              const float wt = wr[dy * K + dx];
#pragma unroll
              for (int j = 0; j < 4; ++j)
                acc[o][j] = fmaf(wt, buf[4 + j + dx - PAD], acc[o][j]);
            }
          }
        }
      }
      // Two nt stores; each instruction's lane runs are ascending contiguous
      // full 448B rows (28 lanes/row) -> full 64B lines, no amplification.
      char* const o0 = outb + (size_t)(rp * 2) * (HW * 4) + q * 16;
      f4 v0 = {acc[0][0], acc[0][1], acc[0][2], acc[0][3]};
      f4 v1 = {acc[1][0], acc[1][1], acc[1][2], acc[1][3]};
      __builtin_nontemporal_store(v0, (f4*)(o0));
      __builtin_nontemporal_store(v1, (f4*)(o0 + HW * 4));
    }
  }
}

__global__ __launch_bounds__(256) void mixconv_lds(
    const float* __restrict__ x, const float* __restrict__ w3,
    const float* __restrict__ w5, const float* __restrict__ w7,
    float* __restrict__ out) {
  __shared__ __align__(16) char lds[NR_MAX * LSTRIDE];  // 16864 B
  const int cy = blockIdx.y;
  const int n = blockIdx.z;
  const int tile0 = blockIdx.x * TILE_H;
  if (cy < 64)
    conv_tile<3>(x, w3, out, lds, cy, cy, n, tile0);
  else if (cy < 128)
    conv_tile<5>(x, w5, out, lds, cy, cy - 64, n, tile0);
  else
    conv_tile<7>(x, w7, out, lds, cy, cy - 128, n, tile0);
}

extern "C" void kernel_launch(void* const* d_in, const int* in_sizes, int n_in,
                              void* d_out, int out_size, void* d_ws,
                              size_t ws_size, hipStream_t stream) {
  const float* x = (const float*)d_in[0];
  const float* w3 = (const float*)d_in[1];
  const float* w5 = (const float*)d_in[2];
  const float* w7 = (const float*)d_in[3];
  float* out = (float*)d_out;

  const dim3 grid(HW / TILE_H, C_TOTAL, N_BATCH);  // 4 x 192 x 32
  const dim3 block(256);
  mixconv_lds<<<grid, block, 0, stream>>>(x, w3, w5, w7, out);
}